// Round 1
// baseline (116.965 us; speedup 1.0000x reference)
//
#include <hip/hip_runtime.h>

// Problem constants (match reference)
constexpr int kHW = 1024 * 1024;
constexpr int kB  = 4;
constexpr int kChunksPerImage = kHW / 4;            // 262144 = 2^18
constexpr int kNChunk = kB * kChunksPerImage;       // 1048576 float4-chunks
constexpr int kM  = 17;
constexpr int kM3 = kM * kM * kM;                   // 4913 cells, *3 ch

// 1D LUT lerp from pre-paired LDS table: s1[c*64+i] = (l[i], l[i+1])
__device__ __forceinline__ float apply1d(const float2* __restrict__ s1, int c, float v) {
    float xs = v * 63.0f;
    int i0 = (int)xs;                 // v >= 0 so trunc == floor
    i0 = min(max(i0, 0), 62);
    float f = xs - (float)i0;
    float2 p = s1[(c << 6) + i0];
    return fmaf(f, p.y - p.x, p.x);
}

__global__ __launch_bounds__(512) void lut_apply_kernel(
    const float* __restrict__ x,
    const float* __restrict__ lut1d,   // [3][64]
    const float* __restrict__ lut3d,   // [17][17][17][3]
    float* __restrict__ out)
{
    __shared__ float  s3[kM3 * 3];     // 58,956 B
    __shared__ float2 s1[3 * 64];      //  1,536 B  (60.5 KB total, <64KB/WG)

    for (int i = threadIdx.x; i < kM3 * 3; i += blockDim.x) s3[i] = lut3d[i];
    for (int i = threadIdx.x; i < 3 * 64; i += blockDim.x) {
        int c = i >> 6, j = i & 63;
        float a = lut1d[(c << 6) + j];
        float b = lut1d[(c << 6) + (j < 63 ? j + 1 : 63)];
        s1[i] = make_float2(a, b);
    }
    __syncthreads();

    const int tid = blockIdx.x * blockDim.x + threadIdx.x;
    const int nthreads = gridDim.x * blockDim.x;

    for (int q = tid; q < kNChunk; q += nthreads) {
        const int b   = q >> 18;                       // image index
        const int rem = q & (kChunksPerImage - 1);     // chunk within image
        const size_t pR = (size_t)(b * 3 + 0) * kHW + 4 * (size_t)rem;
        const size_t pG = (size_t)(b * 3 + 1) * kHW + 4 * (size_t)rem;
        const size_t pB = (size_t)(b * 3 + 2) * kHW + 4 * (size_t)rem;

        const float4 r4 = *(const float4*)(x + pR);
        const float4 g4 = *(const float4*)(x + pG);
        const float4 b4 = *(const float4*)(x + pB);

        const float rin[4] = {r4.x, r4.y, r4.z, r4.w};
        const float gin[4] = {g4.x, g4.y, g4.z, g4.w};
        const float bin[4] = {b4.x, b4.y, b4.z, b4.w};
        float ro[4], go[4], bo[4];

        #pragma unroll
        for (int k = 0; k < 4; ++k) {
            // --- 1D LUT + clip ---
            float yr = apply1d(s1, 0, rin[k]);
            float yg = apply1d(s1, 1, gin[k]);
            float yb = apply1d(s1, 2, bin[k]);
            yr = fminf(fmaxf(yr, 0.0f), 1.0f);
            yg = fminf(fmaxf(yg, 0.0f), 1.0f);
            yb = fminf(fmaxf(yb, 0.0f), 1.0f);

            // --- 3D LUT trilinear ---
            float xr = yr * 16.0f, xg = yg * 16.0f, xb = yb * 16.0f;
            int ir = min((int)xr, 15);
            int ig = min((int)xg, 15);
            int ib = min((int)xb, 15);
            float fr = xr - (float)ir;
            float fg = xg - (float)ig;
            float fb = xb - (float)ib;

            const int base = ((ir * 17 + ig) * 17 + ib) * 3;
            // corner offsets: db=+3, dg=+51, dr=+867 (floats)
            #pragma unroll
            for (int ch = 0; ch < 3; ++ch) {
                const float v000 = s3[base + ch];
                const float v001 = s3[base + ch + 3];
                const float v010 = s3[base + ch + 51];
                const float v011 = s3[base + ch + 54];
                const float v100 = s3[base + ch + 867];
                const float v101 = s3[base + ch + 870];
                const float v110 = s3[base + ch + 918];
                const float v111 = s3[base + ch + 921];

                float v00 = fmaf(fb, v001 - v000, v000);
                float v01 = fmaf(fb, v011 - v010, v010);
                float v10 = fmaf(fb, v101 - v100, v100);
                float v11 = fmaf(fb, v111 - v110, v110);
                float v0  = fmaf(fg, v01 - v00, v00);
                float v1  = fmaf(fg, v11 - v10, v10);
                float res = fmaf(fr, v1 - v0, v0);
                if (ch == 0) ro[k] = res;
                else if (ch == 1) go[k] = res;
                else bo[k] = res;
            }
        }

        *(float4*)(out + pR) = make_float4(ro[0], ro[1], ro[2], ro[3]);
        *(float4*)(out + pG) = make_float4(go[0], go[1], go[2], go[3]);
        *(float4*)(out + pB) = make_float4(bo[0], bo[1], bo[2], bo[3]);
    }
}

extern "C" void kernel_launch(void* const* d_in, const int* in_sizes, int n_in,
                              void* d_out, int out_size, void* d_ws, size_t ws_size,
                              hipStream_t stream) {
    const float* x     = (const float*)d_in[0];
    const float* lut1d = (const float*)d_in[1];
    const float* lut3d = (const float*)d_in[2];
    float* out = (float*)d_out;

    dim3 grid(512), block(512);
    hipLaunchKernelGGL(lut_apply_kernel, grid, block, 0, stream, x, lut1d, lut3d, out);
}

// Round 2
// 111.350 us; speedup vs baseline: 1.0504x; 1.0504x over previous
//
#include <hip/hip_runtime.h>

// Problem constants (match reference)
constexpr int kHW = 1024 * 1024;
constexpr int kB  = 4;
constexpr int kChunksPerImage = kHW / 4;            // 262144 = 2^18
constexpr int kNChunk = kB * kChunksPerImage;       // 1048576 float4-chunks
constexpr int kM  = 17;
constexpr int kM3 = kM * kM * kM;                   // 4913 cells

__device__ __forceinline__ float lerp1(float a, float b, float t) {
    return fmaf(t, b - a, a);
}
__device__ __forceinline__ float2 lerp2(float2 a, float2 b, float t) {
    return make_float2(fmaf(t, b.x - a.x, a.x), fmaf(t, b.y - a.y, a.y));
}

// 1D LUT lerp from pre-paired LDS table: s1[c*64+i] = (l[i], l[i+1])
__device__ __forceinline__ float apply1d(const float2* __restrict__ s1, int c, float v) {
    float xs = v * 63.0f;
    int i0 = (int)xs;                 // v >= 0 so trunc == floor
    i0 = min(max(i0, 0), 62);
    float f = xs - (float)i0;
    float2 p = s1[(c << 6) + i0];
    return fmaf(f, p.y - p.x, p.x);
}

__global__ __launch_bounds__(512) void lut_apply_kernel(
    const float* __restrict__ x,
    const float* __restrict__ lut1d,   // [3][64]
    const float* __restrict__ lut3d,   // [17][17][17][3]
    float* __restrict__ out)
{
    // 3D LUT split: sA[cell] = (c0, c1), sB[cell] = c2.
    // b-adjacent cells are contiguous -> ds_read2_b64 / ds_read2_b32 pairs.
    __shared__ float2 sA[kM3];         // 39,304 B
    __shared__ float  sB[kM3];         // 19,652 B
    __shared__ float2 s1[3 * 64];      //  1,536 B   (60.5 KB total)

    for (int i = threadIdx.x; i < kM3; i += blockDim.x) {
        sA[i] = make_float2(lut3d[i * 3], lut3d[i * 3 + 1]);
        sB[i] = lut3d[i * 3 + 2];
    }
    for (int i = threadIdx.x; i < 3 * 64; i += blockDim.x) {
        int c = i >> 6, j = i & 63;
        float a = lut1d[(c << 6) + j];
        float b = lut1d[(c << 6) + (j < 63 ? j + 1 : 63)];
        s1[i] = make_float2(a, b);
    }
    __syncthreads();

    const int tid = blockIdx.x * blockDim.x + threadIdx.x;
    const int nthreads = gridDim.x * blockDim.x;

    for (int q = tid; q < kNChunk; q += nthreads) {
        const int b   = q >> 18;                       // image index
        const int rem = q & (kChunksPerImage - 1);     // chunk within image
        const size_t pR = (size_t)(b * 3 + 0) * kHW + 4 * (size_t)rem;
        const size_t pG = (size_t)(b * 3 + 1) * kHW + 4 * (size_t)rem;
        const size_t pB = (size_t)(b * 3 + 2) * kHW + 4 * (size_t)rem;

        const float4 r4 = *(const float4*)(x + pR);
        const float4 g4 = *(const float4*)(x + pG);
        const float4 b4 = *(const float4*)(x + pB);

        const float rin[4] = {r4.x, r4.y, r4.z, r4.w};
        const float gin[4] = {g4.x, g4.y, g4.z, g4.w};
        const float bin[4] = {b4.x, b4.y, b4.z, b4.w};
        float ro[4], go[4], bo[4];

        #pragma unroll
        for (int k = 0; k < 4; ++k) {
            // --- 1D LUT + clip ---
            float yr = apply1d(s1, 0, rin[k]);
            float yg = apply1d(s1, 1, gin[k]);
            float yb = apply1d(s1, 2, bin[k]);
            yr = fminf(fmaxf(yr, 0.0f), 1.0f);
            yg = fminf(fmaxf(yg, 0.0f), 1.0f);
            yb = fminf(fmaxf(yb, 0.0f), 1.0f);

            // --- 3D LUT trilinear ---
            float xr = yr * 16.0f, xg = yg * 16.0f, xb = yb * 16.0f;
            int ir = min((int)xr, 15);
            int ig = min((int)xg, 15);
            int ib = min((int)xb, 15);
            float fr = xr - (float)ir;
            float fg = xg - (float)ig;
            float fb = xb - (float)ib;

            const int cell = (ir * 17 + ig) * 17 + ib;   // db=1, dg=17, dr=289
            const float2* pA  = sA + cell;
            const float2* pA2 = sA + cell + 289;
            const float*  qB  = sB + cell;
            const float*  qB2 = sB + cell + 289;

            // 8 corners of (c0,c1): 4x ds_read2_b64
            float2 a000 = pA[0],  a001 = pA[1];
            float2 a010 = pA[17], a011 = pA[18];
            float2 a100 = pA2[0],  a101 = pA2[1];
            float2 a110 = pA2[17], a111 = pA2[18];
            // 8 corners of c2: 4x ds_read2_b32
            float c000 = qB[0],  c001 = qB[1];
            float c010 = qB[17], c011 = qB[18];
            float c100 = qB2[0],  c101 = qB2[1];
            float c110 = qB2[17], c111 = qB2[18];

            // interpolate along b, then g, then r
            float2 a00 = lerp2(a000, a001, fb);
            float2 a01 = lerp2(a010, a011, fb);
            float2 a10 = lerp2(a100, a101, fb);
            float2 a11 = lerp2(a110, a111, fb);
            float  c00 = lerp1(c000, c001, fb);
            float  c01 = lerp1(c010, c011, fb);
            float  c10 = lerp1(c100, c101, fb);
            float  c11 = lerp1(c110, c111, fb);

            float2 a0 = lerp2(a00, a01, fg);
            float2 a1 = lerp2(a10, a11, fg);
            float  c0 = lerp1(c00, c01, fg);
            float  c1 = lerp1(c10, c11, fg);

            float2 aF = lerp2(a0, a1, fr);
            float  cF = lerp1(c0, c1, fr);

            ro[k] = aF.x;
            go[k] = aF.y;
            bo[k] = cF;
        }

        *(float4*)(out + pR) = make_float4(ro[0], ro[1], ro[2], ro[3]);
        *(float4*)(out + pG) = make_float4(go[0], go[1], go[2], go[3]);
        *(float4*)(out + pB) = make_float4(bo[0], bo[1], bo[2], bo[3]);
    }
}

extern "C" void kernel_launch(void* const* d_in, const int* in_sizes, int n_in,
                              void* d_out, int out_size, void* d_ws, size_t ws_size,
                              hipStream_t stream) {
    const float* x     = (const float*)d_in[0];
    const float* lut1d = (const float*)d_in[1];
    const float* lut3d = (const float*)d_in[2];
    float* out = (float*)d_out;

    dim3 grid(512), block(512);
    hipLaunchKernelGGL(lut_apply_kernel, grid, block, 0, stream, x, lut1d, lut3d, out);
}

// Round 3
// 108.315 us; speedup vs baseline: 1.0799x; 1.0280x over previous
//
#include <hip/hip_runtime.h>
#include <hip/hip_fp16.h>

// Problem constants (match reference)
constexpr int kHW = 1024 * 1024;
constexpr int kB  = 4;
constexpr int kPairsPerImage = kHW / 2;             // 524288 = 2^19
constexpr int kNPair = kB * kPairsPerImage;         // 2097152 float2-chunks
constexpr int kM  = 17;
constexpr int kM3 = kM * kM * kM;                   // 4913 cells

constexpr int kBlock = 512;
constexpr int kGrid  = 1024;                        // 4 blocks/CU on 256 CUs

__device__ __forceinline__ float h2f_lo(unsigned int u) {
    __half2 h = *reinterpret_cast<__half2*>(&u);
    return __low2float(h);
}

// 1D LUT lerp from pre-paired LDS table: s1[c*64+i] = (l[i], l[i+1])  (fp32, exact)
__device__ __forceinline__ float apply1d(const float2* __restrict__ s1, int c, float v) {
    float xs = v * 63.0f;
    int i0 = (int)xs;
    i0 = min(max(i0, 0), 62);
    float f = xs - (float)i0;
    float2 p = s1[(c << 6) + i0];
    return fmaf(f, p.y - p.x, p.x);
}

struct F3 { float x, y, z; };

// Trilinear from fp16-packed LDS LUT: s3[cell] = {h(c0)|h(c1), h(c2)|0}
__device__ __forceinline__ F3 tri3d(const uint2* __restrict__ s3,
                                    float yr, float yg, float yb) {
    float xr = yr * 16.0f, xg = yg * 16.0f, xb = yb * 16.0f;
    int ir = min((int)xr, 15);
    int ig = min((int)xg, 15);
    int ib = min((int)xb, 15);
    float fr = xr - (float)ir;
    float fg = xg - (float)ig;
    float fb = xb - (float)ib;

    const int cell = (ir * 17 + ig) * 17 + ib;      // db=1, dg=17, dr=289

    // One ds_read2_b64 per (r,g) corner pair fetches both b corners.
    auto blerp = [&](const uint2* __restrict__ p) -> F3 {
        uint2 e0 = p[0];   // b corner
        uint2 e1 = p[1];   // b+1 corner
        float2 a01 = __half22float2(*reinterpret_cast<__half2*>(&e0.x));
        float  a2  = h2f_lo(e0.y);
        float2 b01 = __half22float2(*reinterpret_cast<__half2*>(&e1.x));
        float  b2  = h2f_lo(e1.y);
        F3 r;
        r.x = fmaf(fb, b01.x - a01.x, a01.x);
        r.y = fmaf(fb, b01.y - a01.y, a01.y);
        r.z = fmaf(fb, b2 - a2, a2);
        return r;
    };

    F3 v00 = blerp(s3 + cell);            // (r0,g0)
    F3 v01 = blerp(s3 + cell + 17);       // (r0,g1)
    F3 v10 = blerp(s3 + cell + 289);      // (r1,g0)
    F3 v11 = blerp(s3 + cell + 306);      // (r1,g1)

    F3 v0, v1, vf;
    v0.x = fmaf(fg, v01.x - v00.x, v00.x);
    v0.y = fmaf(fg, v01.y - v00.y, v00.y);
    v0.z = fmaf(fg, v01.z - v00.z, v00.z);
    v1.x = fmaf(fg, v11.x - v10.x, v10.x);
    v1.y = fmaf(fg, v11.y - v10.y, v10.y);
    v1.z = fmaf(fg, v11.z - v10.z, v10.z);
    vf.x = fmaf(fr, v1.x - v0.x, v0.x);
    vf.y = fmaf(fr, v1.y - v0.y, v0.y);
    vf.z = fmaf(fr, v1.z - v0.z, v0.z);
    return vf;
}

__global__ __launch_bounds__(kBlock, 8) void lut_apply_kernel(
    const float* __restrict__ x,
    const float* __restrict__ lut1d,   // [3][64]
    const float* __restrict__ lut3d,   // [17][17][17][3]
    float* __restrict__ out)
{
    __shared__ uint2  s3[kM3];         // 39,304 B  fp16-packed 3D LUT
    __shared__ float2 s1[3 * 64];      //  1,536 B  fp32 paired 1D LUT
                                       // total 40,840 B -> 4 blocks/CU

    for (int i = threadIdx.x; i < kM3; i += kBlock) {
        float c0 = lut3d[3 * i], c1 = lut3d[3 * i + 1], c2 = lut3d[3 * i + 2];
        __half2 h01 = __floats2half2_rn(c0, c1);
        __half2 h2p = __floats2half2_rn(c2, 0.0f);
        uint2 e;
        e.x = *reinterpret_cast<unsigned int*>(&h01);
        e.y = *reinterpret_cast<unsigned int*>(&h2p);
        s3[i] = e;
    }
    for (int i = threadIdx.x; i < 3 * 64; i += kBlock) {
        int c = i >> 6, j = i & 63;
        float a = lut1d[(c << 6) + j];
        float b = lut1d[(c << 6) + (j < 63 ? j + 1 : 63)];
        s1[i] = make_float2(a, b);
    }
    __syncthreads();

    const int tid = blockIdx.x * kBlock + threadIdx.x;
    const int nthreads = kGrid * kBlock;

    for (int q = tid; q < kNPair; q += nthreads) {
        const int b   = q >> 19;                       // image index
        const int rem = q & (kPairsPerImage - 1);      // pair within image
        const size_t pR = (size_t)(b * 3 + 0) * kHW + 2 * (size_t)rem;
        const size_t pG = (size_t)(b * 3 + 1) * kHW + 2 * (size_t)rem;
        const size_t pB = (size_t)(b * 3 + 2) * kHW + 2 * (size_t)rem;

        const float2 r2 = *(const float2*)(x + pR);
        const float2 g2 = *(const float2*)(x + pG);
        const float2 b2 = *(const float2*)(x + pB);

        float ro[2], go[2], bo[2];
        const float rin[2] = {r2.x, r2.y};
        const float gin[2] = {g2.x, g2.y};
        const float bin[2] = {b2.x, b2.y};

        #pragma unroll
        for (int k = 0; k < 2; ++k) {
            float yr = apply1d(s1, 0, rin[k]);
            float yg = apply1d(s1, 1, gin[k]);
            float yb = apply1d(s1, 2, bin[k]);
            yr = fminf(fmaxf(yr, 0.0f), 1.0f);
            yg = fminf(fmaxf(yg, 0.0f), 1.0f);
            yb = fminf(fmaxf(yb, 0.0f), 1.0f);

            F3 v = tri3d(s3, yr, yg, yb);
            ro[k] = v.x; go[k] = v.y; bo[k] = v.z;
        }

        *(float2*)(out + pR) = make_float2(ro[0], ro[1]);
        *(float2*)(out + pG) = make_float2(go[0], go[1]);
        *(float2*)(out + pB) = make_float2(bo[0], bo[1]);
    }
}

extern "C" void kernel_launch(void* const* d_in, const int* in_sizes, int n_in,
                              void* d_out, int out_size, void* d_ws, size_t ws_size,
                              hipStream_t stream) {
    const float* x     = (const float*)d_in[0];
    const float* lut1d = (const float*)d_in[1];
    const float* lut3d = (const float*)d_in[2];
    float* out = (float*)d_out;

    hipLaunchKernelGGL(lut_apply_kernel, dim3(kGrid), dim3(kBlock), 0, stream,
                       x, lut1d, lut3d, out);
}